// Round 17
// baseline (22.143 us; speedup 1.0000x reference)
//
#include <hip/hip_runtime.h>

// VectorQuantizer on MI355X — v13: v12 + LDS-transpose cooperative store.
// latents: [64, 64, 32, 32] f32, embedding: [512, 64] f32.
// d_out: quantized_st [64,64,32,32] f32 (4194304 elems) then vq_loss scalar f32.
// Math: quantized_st == embedding[argmin d2], vq_loss == 1.25 * mean((q - x)^2).
// Identity: per position, (q-x)^2 summed over d = (winning_score - 2) + ||x||^2,
// where score = ||w||^2 + 2 - 2 x.w (the +2 bias keeps packed scores positive).
//
// v13 change (single-variable vs v12): the output path. Gather stays
// row-contiguous (4 threads/position, exact f32 64B quarters of the winning
// emb row) but lands in a 32KB LDS transpose buffer T[d][p]; after a barrier
// the block stores f32x4 along hw — 4 store instrs/thread, 2x512B contiguous
// segments per wave-instr (was 16 scalar instrs, 4x64B segments).

#define NUM_EMB 512
#define DIM 64
#define HW 1024
#define TOTAL 4194304
#define FUSED_BLOCKS 512    // 512 threads = 8 waves; 128 positions per block

typedef __attribute__((ext_vector_type(8))) short bf16x8;
typedef __attribute__((ext_vector_type(4))) float f32x4;

// d_ws layout: [0, 2048) : float partial[512]

__device__ __forceinline__ unsigned short f32_to_bf16_rne(float f) {
    unsigned int b = __builtin_bit_cast(unsigned int, f);
    return (unsigned short)((b + 0x7FFFu + ((b >> 16) & 1u)) >> 16);
}

__device__ __forceinline__ unsigned int umin32(unsigned int a, unsigned int b) {
    return a < b ? a : b;
}

// Wave w owns codes [w*64, w*64+64). Lane l: c=l&15, g=l>>4.
// A-frag af[kt][f]: code kw+kt*16+c, dims f*32+g*8..+7, bf16(-2w).
// x staged in LDS as [128 pos][8 chunks of 16B], chunk ch stored at ch^(pos&7).
// B-frag for pos-tile pt: row pt*16+c, logical chunk f*4+g -> phys ^(c&7).
// MFMA D: col=lane&15=position, row=g*4+r -> acc[r] = biased score of code
// kw+kt*16+g*4+r at position pt*16+c.  Packed argmin: u32 =
// (score_bits & ~511) | k; LDS atomicMin combines waves; strict min keeps
// smallest k on masked-score ties (jnp.argmin tie-break).
__global__ __launch_bounds__(512, 4) void fused_vq_kernel(
    const float* __restrict__ latents, const float* __restrict__ emb,
    float* __restrict__ out, float* __restrict__ partial) {
    __shared__ char xl[16384];                     // swizzled bf16 x
    __shared__ float T[DIM][128];                  // 32KB output transpose
    __shared__ unsigned int bestmin[128];
    __shared__ float wsum[8];

    const int tid  = threadIdx.x;
    const int wave = tid >> 6;                     // 0..7
    const int l    = tid & 63;
    const int c    = l & 15;
    const int g    = l >> 4;

    const int n0  = blockIdx.x * 128;              // 128 positions, same b row
    const int b   = n0 >> 10;
    const int hw0 = n0 & 1023;

    // ---- PHASE A: issue x-loads (16 per thread, coalesced) ----
    const int pos = tid & 127;                     // position this thread stages
    const int ch2 = tid >> 7;                      // dim-quarter (16 dims)
    const float* xp = latents + (size_t)b * (DIM * HW) + hw0 + pos;
    float xv[16];
#pragma unroll
    for (int j = 0; j < 16; ++j) xv[j] = xp[(ch2 * 16 + j) * HW];

    if (tid < 128) bestmin[tid] = 0xFFFFFFFFu;

    // ---- PHASE B: build W-frags from raw emb (L3/L2-hot, 16KB per wave) ----
    const int kw = wave * 64;
    bf16x8 af[4][2];
    f32x4  ww4[4];
#pragma unroll
    for (int kt = 0; kt < 4; ++kt) {
        const float* wrow = emb + (kw + kt * 16 + c) * 64;
        const f32x4 w0a = *(const f32x4*)(wrow + g * 8);
        const f32x4 w0b = *(const f32x4*)(wrow + g * 8 + 4);
        const f32x4 w1a = *(const f32x4*)(wrow + 32 + g * 8);
        const f32x4 w1b = *(const f32x4*)(wrow + 32 + g * 8 + 4);
        // per-lane partial ||w||^2 over this lane's 16 dims
        float ps = 0.f;
        bf16x8 a0, a1;
#pragma unroll
        for (int j = 0; j < 4; ++j) {
            ps = fmaf(w0a[j], w0a[j], ps);  a0[j]     = (short)f32_to_bf16_rne(-2.0f * w0a[j]);
            ps = fmaf(w0b[j], w0b[j], ps);  a0[j + 4] = (short)f32_to_bf16_rne(-2.0f * w0b[j]);
            ps = fmaf(w1a[j], w1a[j], ps);  a1[j]     = (short)f32_to_bf16_rne(-2.0f * w1a[j]);
            ps = fmaf(w1b[j], w1b[j], ps);  a1[j + 4] = (short)f32_to_bf16_rne(-2.0f * w1b[j]);
        }
        af[kt][0] = a0;
        af[kt][1] = a1;
        // full ||w(kw+kt*16+c)||^2: sum the 4 g-partials (lanes c, c+16, ...)
        float s = ps + __shfl_xor(ps, 16);
        s += __shfl_xor(s, 32);
        // C-operand layout needs codes g*4+r -> gather from lanes (g*4+r)
        f32x4 w4;
#pragma unroll
        for (int r = 0; r < 4; ++r) w4[r] = __shfl(s, g * 4 + r) + 2.0f;
        ww4[kt] = w4;
    }

    // ---- convert x -> bf16, accumulate x^2, write swizzled LDS chunks ----
    float x2a = 0.f, x2b = 0.f;
    unsigned short xb[16];
#pragma unroll
    for (int j = 0; j < 16; ++j) {
        const float v = xv[j];
        if (j & 1) x2a = fmaf(v, v, x2a); else x2b = fmaf(v, v, x2b);
        xb[j] = f32_to_bf16_rne(v);
    }
    const float x2 = x2a + x2b;
#pragma unroll
    for (int h = 0; h < 2; ++h) {
        const int ch = ch2 * 2 + h;
        const int sw = ch ^ (pos & 7);
        *(bf16x8*)(xl + pos * 128 + sw * 16) = *(const bf16x8*)(xb + h * 8);
    }
    __syncthreads();                               // x staged

    // ---- compute: 8 pos-tiles x (4 k-tiles x 2 MFMA) per wave ----
    const int swa = (g ^ (c & 7)) << 4;            // f=0 phys chunk byte
    const int swb = (((4 + g) ^ (c & 7))) << 4;    // f=1 phys chunk byte
#pragma unroll
    for (int pt = 0; pt < 8; ++pt) {
        const char* xrow = xl + (pt * 16 + c) * 128;
        const bf16x8 b0 = *(const bf16x8*)(xrow + swa);
        const bf16x8 b1 = *(const bf16x8*)(xrow + swb);
        unsigned int best = 0xFFFFFFFFu;
#pragma unroll
        for (int kt = 0; kt < 4; ++kt) {
            f32x4 acc = __builtin_amdgcn_mfma_f32_16x16x32_bf16(af[kt][0], b0, ww4[kt], 0, 0, 0);
            acc       = __builtin_amdgcn_mfma_f32_16x16x32_bf16(af[kt][1], b1, acc, 0, 0, 0);
            const unsigned int kb = (unsigned int)(kw + kt * 16 + g * 4);
            const unsigned int t0 = (__builtin_bit_cast(unsigned int, acc[0]) & 0xFFFFFE00u) | (kb + 0);
            const unsigned int t1 = (__builtin_bit_cast(unsigned int, acc[1]) & 0xFFFFFE00u) | (kb + 1);
            const unsigned int t2 = (__builtin_bit_cast(unsigned int, acc[2]) & 0xFFFFFE00u) | (kb + 2);
            const unsigned int t3 = (__builtin_bit_cast(unsigned int, acc[3]) & 0xFFFFFE00u) | (kb + 3);
            best = umin32(umin32(umin32(t0, t1), umin32(t2, t3)), best);
        }
        unsigned int o;
        o = __shfl_xor(best, 16); best = umin32(best, o);
        o = __shfl_xor(best, 32); best = umin32(best, o);
        if (l < 16) atomicMin(&bestmin[pt * 16 + c], best);
    }
    __syncthreads();                               // bestmin final across waves

    // ---- gather winning rows (exact f32, contiguous 64B per thread) and
    //      write into the LDS transpose buffer; loss reduce overlaps ----
    const int p = tid >> 2;                        // position 0..127
    const int q = tid & 3;                         // d-quarter
    const int k = (int)(bestmin[p] & 511u);
    const f32x4* er = (const f32x4*)(emb + k * 64 + q * 16);
    const f32x4 q0 = er[0], q1 = er[1], q2 = er[2], q3 = er[3];

    float contrib = 0.f;
    if (tid < 128)
        contrib = __builtin_bit_cast(float, bestmin[tid] & 0xFFFFFE00u) - 2.0f;
    contrib += x2;
#pragma unroll
    for (int off = 32; off; off >>= 1) contrib += __shfl_xor(contrib, off, 64);
    if (l == 0) wsum[wave] = contrib;

#pragma unroll
    for (int j = 0; j < 4; ++j) T[q * 16 + j][p]      = q0[j];
#pragma unroll
    for (int j = 0; j < 4; ++j) T[q * 16 + 4 + j][p]  = q1[j];
#pragma unroll
    for (int j = 0; j < 4; ++j) T[q * 16 + 8 + j][p]  = q2[j];
#pragma unroll
    for (int j = 0; j < 4; ++j) T[q * 16 + 12 + j][p] = q3[j];
    __syncthreads();                               // T + wsum ready

    if (tid == 0) {
        float tot = 0.f;
#pragma unroll
        for (int i = 0; i < 8; ++i) tot += wsum[i];
        partial[blockIdx.x] = tot;                 // plain store, no atomic
    }

    // ---- cooperative store: f32x4 along hw; per wave-instr 2x512B segments ----
    float* obase = out + (size_t)b * (DIM * HW) + hw0;
#pragma unroll
    for (int i = 0; i < 4; ++i) {
        const int v  = i * 512 + tid;              // 2048 f32x4 vecs
        const int d  = v >> 5;
        const int p4 = (v & 31) * 4;
        const f32x4 qv = *(const f32x4*)&T[d][p4];
        *(f32x4*)(obase + d * HW + p4) = qv;
    }
    // no trailing barrier: stores drain at endpgm
}

__global__ __launch_bounds__(512) void finalize_kernel(
    const float* __restrict__ partial, float* __restrict__ out) {
    const int tid = threadIdx.x;
    double s = (double)partial[tid];
#pragma unroll
    for (int off = 32; off; off >>= 1) s += __shfl_xor(s, off, 64);
    __shared__ double dsum[8];
    if ((tid & 63) == 0) dsum[tid >> 6] = s;
    __syncthreads();
    if (tid == 0) {
        double tot = 0.0;
#pragma unroll
        for (int i = 0; i < 8; ++i) tot += dsum[i];
        out[TOTAL] = (float)(1.25 * tot / (double)TOTAL);
    }
}

extern "C" void kernel_launch(void* const* d_in, const int* in_sizes, int n_in,
                              void* d_out, int out_size, void* d_ws, size_t ws_size,
                              hipStream_t stream) {
    const float* latents = (const float*)d_in[0];
    const float* emb     = (const float*)d_in[1];
    float* out = (float*)d_out;
    float* partial = (float*)d_ws;

    fused_vq_kernel<<<FUSED_BLOCKS, 512, 0, stream>>>(latents, emb, out, partial);
    finalize_kernel<<<1, 512, 0, stream>>>(partial, out);
}

// Round 18
// 21.718 us; speedup vs baseline: 1.0196x; 1.0196x over previous
//
#include <hip/hip_runtime.h>

// VectorQuantizer on MI355X — v14: v12 + hw cvt_pk bf16 conversion + (-2)->x.
// latents: [64, 64, 32, 32] f32, embedding: [512, 64] f32.
// d_out: quantized_st [64,64,32,32] f32 (4194304 elems) then vq_loss scalar f32.
// Math: quantized_st == embedding[argmin d2], vq_loss == 1.25 * mean((q - x)^2).
// Identity: per position, (q-x)^2 summed over d = (winning_score - 2) + ||x||^2,
// score = ||w||^2 + 2 + w.(-2x) = ||w||^2 + 2 - 2 x.w.
//
// v14 changes (VALU cut, structure identical to v12):
//  - all f32->bf16 conversions via v_cvt_pk_bf16_f32 (1 instr / 2 elems,
//    inline asm — no builtin on gfx950), replacing a ~5-op manual RNE;
//  - the -2 scale moved from w (64 elems/thread) to x (16 elems/thread);
//    products bf16(w) * bf16(-2x) are numerically identical to before.

#define NUM_EMB 512
#define DIM 64
#define HW 1024
#define TOTAL 4194304
#define FUSED_BLOCKS 512    // 512 threads = 8 waves; 128 positions per block

typedef __attribute__((ext_vector_type(8))) short bf16x8;
typedef __attribute__((ext_vector_type(4))) float f32x4;
typedef __attribute__((ext_vector_type(4))) int   i32x4;

// d_ws layout: [0, 2048) : float partial[512]

__device__ __forceinline__ int cvt_pk_bf16(float lo, float hi) {
    int r;
    asm("v_cvt_pk_bf16_f32 %0, %1, %2" : "=v"(r) : "v"(lo), "v"(hi));
    return r;
}

__device__ __forceinline__ unsigned int umin32(unsigned int a, unsigned int b) {
    return a < b ? a : b;
}

// Wave w owns codes [w*64, w*64+64). Lane l: c=l&15, g=l>>4.
// A-frag af[kt][f]: code kw+kt*16+c, dims f*32+g*8..+7, bf16(w).
// x staged in LDS as bf16(-2x): [128 pos][8 chunks of 16B], chunk ch at
// ch^(pos&7). B-frag for pos-tile pt: row pt*16+c, logical chunk f*4+g ->
// phys ^(c&7).  MFMA D: col=lane&15=position, row=g*4+r -> acc[r] = biased
// score of code kw+kt*16+g*4+r at position pt*16+c.  Packed argmin:
// u32 = (score_bits & ~511) | k; LDS atomicMin combines waves; strict min
// keeps smallest k on masked-score ties (jnp.argmin tie-break).
__global__ __launch_bounds__(512, 4) void fused_vq_kernel(
    const float* __restrict__ latents, const float* __restrict__ emb,
    float* __restrict__ out, float* __restrict__ partial) {
    __shared__ char xl[16384];                     // swizzled bf16(-2x)
    __shared__ unsigned int bestmin[128];
    __shared__ float wsum[8];

    const int tid  = threadIdx.x;
    const int wave = tid >> 6;                     // 0..7
    const int l    = tid & 63;
    const int c    = l & 15;
    const int g    = l >> 4;

    const int n0  = blockIdx.x * 128;              // 128 positions, same b row
    const int b   = n0 >> 10;
    const int hw0 = n0 & 1023;

    // ---- PHASE A: issue x-loads (16 per thread, coalesced) ----
    const int pos = tid & 127;                     // position this thread stages
    const int ch2 = tid >> 7;                      // dim-quarter (16 dims)
    const float* xp = latents + (size_t)b * (DIM * HW) + hw0 + pos;
    float xv[16];
#pragma unroll
    for (int j = 0; j < 16; ++j) xv[j] = xp[(ch2 * 16 + j) * HW];

    if (tid < 128) bestmin[tid] = 0xFFFFFFFFu;

    // ---- PHASE B: build W-frags from raw emb (L3/L2-hot, 16KB per wave) ----
    const int kw = wave * 64;
    bf16x8 af[4][2];
    f32x4  ww4[4];
#pragma unroll
    for (int kt = 0; kt < 4; ++kt) {
        const float* wrow = emb + (kw + kt * 16 + c) * 64;
        const f32x4 w0a = *(const f32x4*)(wrow + g * 8);
        const f32x4 w0b = *(const f32x4*)(wrow + g * 8 + 4);
        const f32x4 w1a = *(const f32x4*)(wrow + 32 + g * 8);
        const f32x4 w1b = *(const f32x4*)(wrow + 32 + g * 8 + 4);
        // per-lane partial ||w||^2 over this lane's 16 dims
        float ps = 0.f;
#pragma unroll
        for (int j = 0; j < 4; ++j) {
            ps = fmaf(w0a[j], w0a[j], ps); ps = fmaf(w0b[j], w0b[j], ps);
            ps = fmaf(w1a[j], w1a[j], ps); ps = fmaf(w1b[j], w1b[j], ps);
        }
        // pack bf16(w) fragments: 8 cvt_pk per kt
        i32x4 p0, p1;
        p0[0] = cvt_pk_bf16(w0a[0], w0a[1]); p0[1] = cvt_pk_bf16(w0a[2], w0a[3]);
        p0[2] = cvt_pk_bf16(w0b[0], w0b[1]); p0[3] = cvt_pk_bf16(w0b[2], w0b[3]);
        p1[0] = cvt_pk_bf16(w1a[0], w1a[1]); p1[1] = cvt_pk_bf16(w1a[2], w1a[3]);
        p1[2] = cvt_pk_bf16(w1b[0], w1b[1]); p1[3] = cvt_pk_bf16(w1b[2], w1b[3]);
        af[kt][0] = __builtin_bit_cast(bf16x8, p0);
        af[kt][1] = __builtin_bit_cast(bf16x8, p1);
        // full ||w(kw+kt*16+c)||^2: sum the 4 g-partials (lanes c, c+16, ...)
        float s = ps + __shfl_xor(ps, 16);
        s += __shfl_xor(s, 32);
        // C-operand layout needs codes g*4+r -> gather from lanes (g*4+r)
        f32x4 w4;
#pragma unroll
        for (int r = 0; r < 4; ++r) w4[r] = __shfl(s, g * 4 + r) + 2.0f;
        ww4[kt] = w4;
    }

    // ---- convert x -> bf16(-2x), accumulate x^2, swizzled LDS write ----
    float x2a = 0.f, x2b = 0.f;
    float xm[16];
#pragma unroll
    for (int j = 0; j < 16; ++j) {
        const float v = xv[j];
        if (j & 1) x2a = fmaf(v, v, x2a); else x2b = fmaf(v, v, x2b);
        xm[j] = -2.0f * v;
    }
    const float x2 = x2a + x2b;
    i32x4 xpk[2];
#pragma unroll
    for (int h = 0; h < 2; ++h)
#pragma unroll
        for (int j = 0; j < 4; ++j)
            xpk[h][j] = cvt_pk_bf16(xm[h * 8 + 2 * j], xm[h * 8 + 2 * j + 1]);
#pragma unroll
    for (int h = 0; h < 2; ++h) {
        const int ch = ch2 * 2 + h;
        const int sw = ch ^ (pos & 7);
        *(i32x4*)(xl + pos * 128 + sw * 16) = xpk[h];
    }
    __syncthreads();                               // x staged

    // ---- compute: 8 pos-tiles x (4 k-tiles x 2 MFMA) per wave ----
    const int swa = (g ^ (c & 7)) << 4;            // f=0 phys chunk byte
    const int swb = (((4 + g) ^ (c & 7))) << 4;    // f=1 phys chunk byte
#pragma unroll
    for (int pt = 0; pt < 8; ++pt) {
        const char* xrow = xl + (pt * 16 + c) * 128;
        const bf16x8 b0 = *(const bf16x8*)(xrow + swa);
        const bf16x8 b1 = *(const bf16x8*)(xrow + swb);
        unsigned int best = 0xFFFFFFFFu;
#pragma unroll
        for (int kt = 0; kt < 4; ++kt) {
            f32x4 acc = __builtin_amdgcn_mfma_f32_16x16x32_bf16(af[kt][0], b0, ww4[kt], 0, 0, 0);
            acc       = __builtin_amdgcn_mfma_f32_16x16x32_bf16(af[kt][1], b1, acc, 0, 0, 0);
            const unsigned int kb = (unsigned int)(kw + kt * 16 + g * 4);
            const unsigned int t0 = (__builtin_bit_cast(unsigned int, acc[0]) & 0xFFFFFE00u) | (kb + 0);
            const unsigned int t1 = (__builtin_bit_cast(unsigned int, acc[1]) & 0xFFFFFE00u) | (kb + 1);
            const unsigned int t2 = (__builtin_bit_cast(unsigned int, acc[2]) & 0xFFFFFE00u) | (kb + 2);
            const unsigned int t3 = (__builtin_bit_cast(unsigned int, acc[3]) & 0xFFFFFE00u) | (kb + 3);
            best = umin32(umin32(umin32(t0, t1), umin32(t2, t3)), best);
        }
        unsigned int o;
        o = __shfl_xor(best, 16); best = umin32(best, o);
        o = __shfl_xor(best, 32); best = umin32(best, o);
        if (l < 16) atomicMin(&bestmin[pt * 16 + c], best);
    }
    __syncthreads();                               // bestmin final across waves

    // ---- loss: x2 (all threads) + (score-2) (first 128 threads) ----
    float contrib = x2;
    if (tid < 128)
        contrib += __builtin_bit_cast(float, bestmin[tid] & 0xFFFFFE00u) - 2.0f;
#pragma unroll
    for (int off = 32; off; off >>= 1) contrib += __shfl_xor(contrib, off, 64);
    if (l == 0) wsum[wave] = contrib;
    __syncthreads();
    if (tid == 0) {
        float tot = 0.f;
#pragma unroll
        for (int i = 0; i < 8; ++i) tot += wsum[i];
        partial[blockIdx.x] = tot;                 // plain store, no atomic
    }

    // ---- store: 4 threads/position; thread reads its contiguous 64B quarter
    //      of the winning emb row (exact f32), 16 coalesced scalar stores ----
    const int p = tid >> 2;                        // position 0..127
    const int q = tid & 3;                         // d-quarter
    const int k = (int)(bestmin[p] & 511u);
    const f32x4* er = (const f32x4*)(emb + k * 64 + q * 16);
    const f32x4 q0 = er[0], q1 = er[1], q2 = er[2], q3 = er[3];
    float* obase = out + (size_t)b * (DIM * HW) + hw0 + p;
#pragma unroll
    for (int j = 0; j < 4; ++j) obase[(q * 16 + j)      * HW] = q0[j];
#pragma unroll
    for (int j = 0; j < 4; ++j) obase[(q * 16 + 4 + j)  * HW] = q1[j];
#pragma unroll
    for (int j = 0; j < 4; ++j) obase[(q * 16 + 8 + j)  * HW] = q2[j];
#pragma unroll
    for (int j = 0; j < 4; ++j) obase[(q * 16 + 12 + j) * HW] = q3[j];
    // no trailing barrier: stores drain at endpgm
}

__global__ __launch_bounds__(512) void finalize_kernel(
    const float* __restrict__ partial, float* __restrict__ out) {
    const int tid = threadIdx.x;
    double s = (double)partial[tid];
#pragma unroll
    for (int off = 32; off; off >>= 1) s += __shfl_xor(s, off, 64);
    __shared__ double dsum[8];
    if ((tid & 63) == 0) dsum[tid >> 6] = s;
    __syncthreads();
    if (tid == 0) {
        double tot = 0.0;
#pragma unroll
        for (int i = 0; i < 8; ++i) tot += dsum[i];
        out[TOTAL] = (float)(1.25 * tot / (double)TOTAL);
    }
}

extern "C" void kernel_launch(void* const* d_in, const int* in_sizes, int n_in,
                              void* d_out, int out_size, void* d_ws, size_t ws_size,
                              hipStream_t stream) {
    const float* latents = (const float*)d_in[0];
    const float* emb     = (const float*)d_in[1];
    float* out = (float*)d_out;
    float* partial = (float*)d_ws;

    fused_vq_kernel<<<FUSED_BLOCKS, 512, 0, stream>>>(latents, emb, out, partial);
    finalize_kernel<<<1, 512, 0, stream>>>(partial, out);
}